// Round 1
// baseline (90.657 us; speedup 1.0000x reference)
//
#include <hip/hip_runtime.h>
#include <hip/hip_bf16.h>

// Problem constants (fixed shapes from setup_inputs)
constexpr int Hh = 224;
constexpr int Ww = 224;
constexpr int Bb = 8;
constexpr int Kc = 4;
constexpr int RAD = 5;
constexpr int KS = 11;

// Tile config: 32x8 pixels per 256-thread block
constexpr int TX = 32;
constexpr int TY = 8;
constexpr int SW = TX + 2 * RAD;   // 42 (loaded width)
constexpr int SH = TY + 2 * RAD;   // 18 (loaded height)
constexpr int SSTR = SW + 1;       // 43 (odd stride -> no bank conflicts)

__global__ __launch_bounds__(256) void ncut_main(const float* __restrict__ images,
                                                 const float* __restrict__ labels,
                                                 float* __restrict__ acc /*64 floats*/) {
    __shared__ float  simg[SH * SSTR];
    __shared__ float4 slab[SH * SSTR];

    const int b   = blockIdx.z;
    const int x0  = blockIdx.x * TX;
    const int y0  = blockIdx.y * TY;
    const int tid = threadIdx.x;

    const float* imgb = images + (size_t)b * (Hh * Ww);
    const float* labb = labels + (size_t)b * (Kc * Hh * Ww);

    // Stage tile + halo. OOB: img=1e19 (-> weight underflows to exactly 0), labels=0.
    for (int idx = tid; idx < SH * SW; idx += 256) {
        const int lx = idx % SW, ly = idx / SW;
        const int gx = x0 - RAD + lx, gy = y0 - RAD + ly;
        float  iv = 1e19f;
        float4 lv = make_float4(0.f, 0.f, 0.f, 0.f);
        if (gx >= 0 && gx < Ww && gy >= 0 && gy < Hh) {
            const int g = gy * Ww + gx;
            iv = imgb[g] * 255.0f;
            lv.x = labb[g];
            lv.y = labb[Hh * Ww + g];
            lv.z = labb[2 * Hh * Ww + g];
            lv.w = labb[3 * Hh * Ww + g];
        }
        simg[ly * SSTR + lx] = iv;
        slab[ly * SSTR + lx] = lv;
    }
    __syncthreads();

    const int tx = tid & (TX - 1);
    const int ty = tid >> 5;   // 256/32 = 8 rows

    const float c = simg[(ty + RAD) * SSTR + (tx + RAD)];

    float  den = 0.f;
    float4 num = make_float4(0.f, 0.f, 0.f, 0.f);

    constexpr float d2[KS] = {25.f, 16.f, 9.f, 4.f, 1.f, 0.f, 1.f, 4.f, 9.f, 16.f, 25.f};

    for (int dy = 0; dy < KS; ++dy) {
        const float ndy = -d2[dy] * 0.0625f;
        const int rowbase = (ty + dy) * SSTR + tx;
#pragma unroll
        for (int dx = 0; dx < KS; ++dx) {
            const float v    = simg[rowbase + dx];
            const float diff = v - c;
            // exponent = -(d2y+d2x)/16 - diff^2/100, single exp
            const float e = __expf(fmaf(diff * diff, -0.01f, ndy - d2[dx] * 0.0625f));
            const float4 p = slab[rowbase + dx];
            den   += e;
            num.x  = fmaf(e, p.x, num.x);
            num.y  = fmaf(e, p.y, num.y);
            num.z  = fmaf(e, p.z, num.z);
            num.w  = fmaf(e, p.w, num.w);
        }
    }

    const float4 pc = slab[(ty + RAD) * SSTR + (tx + RAD)];

    float vals[8] = {pc.x * num.x, pc.y * num.y, pc.z * num.z, pc.w * num.w,
                     pc.x * den,   pc.y * den,   pc.z * den,   pc.w * den};

    // wave (64-lane) reduction
#pragma unroll
    for (int i = 0; i < 8; ++i) {
        float v = vals[i];
#pragma unroll
        for (int off = 32; off > 0; off >>= 1) v += __shfl_down(v, off, 64);
        vals[i] = v;
    }

    __shared__ float red[4][8];
    const int wave = tid >> 6;
    const int lane = tid & 63;
    if (lane == 0) {
#pragma unroll
        for (int i = 0; i < 8; ++i) red[wave][i] = vals[i];
    }
    __syncthreads();

    if (tid < 8) {
        const float s = red[0][tid] + red[1][tid] + red[2][tid] + red[3][tid];
        const int k     = tid & 3;
        const int isden = tid >> 2;  // 0 = num-part, 1 = den-part
        atomicAdd(&acc[isden * 32 + b * Kc + k], s);
    }
}

__global__ void ncut_final(const float* __restrict__ acc, float* __restrict__ out) {
    const int tid = threadIdx.x;  // 64 threads
    float r = 0.f;
    if (tid < 32) {
        r = fabsf(acc[tid] / acc[32 + tid]);
    }
#pragma unroll
    for (int off = 32; off > 0; off >>= 1) r += __shfl_down(r, off, 64);
    if (tid == 0) out[0] = (float)Kc - r * (1.0f / (float)Bb);
}

extern "C" void kernel_launch(void* const* d_in, const int* in_sizes, int n_in,
                              void* d_out, int out_size, void* d_ws, size_t ws_size,
                              hipStream_t stream) {
    const float* images = (const float*)d_in[0];
    const float* labels = (const float*)d_in[1];
    float* out = (float*)d_out;
    float* acc = (float*)d_ws;  // 64 floats: [0..31]=num sums, [32..63]=den sums

    hipMemsetAsync(acc, 0, 64 * sizeof(float), stream);

    dim3 grid(Ww / TX, Hh / TY, Bb);  // 7 x 28 x 8
    ncut_main<<<grid, 256, 0, stream>>>(images, labels, acc);
    ncut_final<<<1, 64, 0, stream>>>(acc, out);
}

// Round 2
// 83.951 us; speedup vs baseline: 1.0799x; 1.0799x over previous
//
#include <hip/hip_runtime.h>
#include <hip/hip_bf16.h>

typedef float f2 __attribute__((ext_vector_type(2)));
typedef float f4 __attribute__((ext_vector_type(4)));

constexpr int Hh = 224, Ww = 224, Bb = 8, Kc = 4, RAD = 5;

// 256 threads = 32x8; each thread computes 2 vertically-adjacent pixels -> 32x16 tile
constexpr int TX = 32;
constexpr int TILEH = 16;
constexpr int SW = TX + 2 * RAD;      // 42
constexpr int SH = TILEH + 2 * RAD;   // 26
constexpr int SSTR = SW + 1;          // 43 (odd -> conflict-free; col 42 = pad column)
constexpr int GXD = Ww / TX;          // 7
constexpr int GYD = Hh / TILEH;       // 14
constexpr int PB = GXD * GYD;         // 98 blocks per batch image

constexpr float LOG2E = 1.44269504f;
constexpr float KI = -0.01f * LOG2E;         // intensity coeff (pre-scaled for exp2)
constexpr float DSC = -0.0625f * LOG2E;      // dist coeff     (pre-scaled for exp2)
// d^2 per kernel offset; index 11 is the pad column (value irrelevant, weight = 0)
constexpr float D2[12] = {25.f,16.f,9.f,4.f,1.f,0.f,1.f,4.f,9.f,16.f,25.f,0.f};

static __device__ inline f4 splat4(float x) { return (f4){x, x, x, x}; }

__global__ __launch_bounds__(256, 3) void ncut_main(const float* __restrict__ images,
                                                    const float* __restrict__ labels,
                                                    float* __restrict__ acc) {
    __shared__ float simg[SH * SSTR];
    __shared__ f4    slab[SH * SSTR];
    __shared__ float red[4][8];

    const int b   = blockIdx.z;
    const int x0  = blockIdx.x * TX;
    const int y0  = blockIdx.y * TILEH;
    const int tid = threadIdx.x;

    const float* imgb = images + (size_t)b * (Hh * Ww);
    const float* labb = labels + (size_t)b * (Kc * Hh * Ww);

    // Stage tile + halo (incl. the stride-pad column as OOB).
    // OOB: img = 1e19 -> single-exp weight underflows to exactly 0; labels = 0.
    for (int idx = tid; idx < SH * SSTR; idx += 256) {
        const int lx = idx % SSTR, ly = idx / SSTR;
        const int gx = x0 - RAD + lx, gy = y0 - RAD + ly;
        float iv = 1e19f;
        f4 lv = (f4){0.f, 0.f, 0.f, 0.f};
        if (lx < SW && gx >= 0 && gx < Ww && gy >= 0 && gy < Hh) {
            const int g = gy * Ww + gx;
            iv = imgb[g] * 255.0f;
            lv = (f4){labb[g], labb[Hh * Ww + g], labb[2 * Hh * Ww + g], labb[3 * Hh * Ww + g]};
        }
        simg[idx] = iv;
        slab[idx] = lv;
    }
    __syncthreads();

    const int tx = tid & 31;
    const int ty = tid >> 5;      // 0..7
    const int r0 = 2 * ty;        // top LDS row of this thread's 12-row window

    const float c0 = simg[(r0 + RAD) * SSTR + tx + RAD];
    const float c1 = simg[(r0 + RAD + 1) * SSTR + tx + RAD];

    f4 num0 = splat4(0.f), num1 = splat4(0.f);
    f2 den0 = (f2){0.f, 0.f}, den1 = (f2){0.f, 0.f};

    // 12 rows: row dr serves center0 (dy=dr, dr<11) and center1 (dy=dr-1, dr>=1)
#pragma unroll
    for (int dr = 0; dr < 12; ++dr) {
        const int rowoff = (r0 + dr) * SSTR + tx;
#pragma unroll
        for (int i = 0; i < 6; ++i) {
            const f2 v  = (f2){simg[rowoff + 2 * i], simg[rowoff + 2 * i + 1]};
            const f4 p0 = slab[rowoff + 2 * i];
            const f4 p1 = slab[rowoff + 2 * i + 1];
            if (dr < 11) {
                const f2 base = (f2){(D2[2 * i] + D2[dr]) * DSC,
                                     (D2[2 * i + 1] + D2[dr]) * DSC};
                const f2 d = v - c0;
                const f2 a = __builtin_elementwise_fma(d * KI, d, base);
                const float e0 = __builtin_amdgcn_exp2f(a.x);
                const float e1 = __builtin_amdgcn_exp2f(a.y);
                den0 += (f2){e0, e1};
                num0 = __builtin_elementwise_fma(splat4(e0), p0, num0);
                num0 = __builtin_elementwise_fma(splat4(e1), p1, num0);
            }
            if (dr >= 1) {
                const f2 base = (f2){(D2[2 * i] + D2[dr - 1]) * DSC,
                                     (D2[2 * i + 1] + D2[dr - 1]) * DSC};
                const f2 d = v - c1;
                const f2 a = __builtin_elementwise_fma(d * KI, d, base);
                const float e0 = __builtin_amdgcn_exp2f(a.x);
                const float e1 = __builtin_amdgcn_exp2f(a.y);
                den1 += (f2){e0, e1};
                num1 = __builtin_elementwise_fma(splat4(e0), p0, num1);
                num1 = __builtin_elementwise_fma(splat4(e1), p1, num1);
            }
        }
    }

    const f4 pc0 = slab[(r0 + RAD) * SSTR + tx + RAD];
    const f4 pc1 = slab[(r0 + RAD + 1) * SSTR + tx + RAD];
    const float dn0 = den0.x + den0.y;
    const float dn1 = den1.x + den1.y;

    const f4 numv = pc0 * num0 + pc1 * num1;                 // per-class sum p_f * num
    const f4 denv = pc0 * dn0 + pc1 * dn1;                   // per-class sum p_f * den

    float vals[8] = {numv.x, numv.y, numv.z, numv.w, denv.x, denv.y, denv.z, denv.w};

#pragma unroll
    for (int i = 0; i < 8; ++i) {
        float v = vals[i];
#pragma unroll
        for (int off = 32; off > 0; off >>= 1) v += __shfl_down(v, off, 64);
        vals[i] = v;
    }

    const int wave = tid >> 6, lane = tid & 63;
    if (lane == 0) {
#pragma unroll
        for (int i = 0; i < 8; ++i) red[wave][i] = vals[i];
    }
    __syncthreads();

    if (tid < 8) {
        const int gid = blockIdx.x + GXD * blockIdx.y + GXD * GYD * blockIdx.z;
        acc[gid * 8 + tid] = red[0][tid] + red[1][tid] + red[2][tid] + red[3][tid];
    }
}

__global__ void ncut_final(const float* __restrict__ acc, float* __restrict__ out) {
    const int t = threadIdx.x;          // 64
    const int k = t & 3, b = (t >> 2) & 7, part = t >> 5;
    float s = 0.f;
    for (int j = 0; j < PB; ++j) s += acc[(b * PB + j) * 8 + k + 4 * part];
    const float den = __shfl(s, (t + 32) & 63, 64);
    float r = (t < 32) ? fabsf(s / den) : 0.f;
#pragma unroll
    for (int off = 32; off > 0; off >>= 1) r += __shfl_down(r, off, 64);
    if (t == 0) out[0] = (float)Kc - r * (1.0f / (float)Bb);
}

extern "C" void kernel_launch(void* const* d_in, const int* in_sizes, int n_in,
                              void* d_out, int out_size, void* d_ws, size_t ws_size,
                              hipStream_t stream) {
    const float* images = (const float*)d_in[0];
    const float* labels = (const float*)d_in[1];
    float* out = (float*)d_out;
    float* acc = (float*)d_ws;  // PB*Bb blocks * 8 partials, fully overwritten each launch

    dim3 grid(GXD, GYD, Bb);    // 7 x 14 x 8
    ncut_main<<<grid, 256, 0, stream>>>(images, labels, acc);
    ncut_final<<<1, 64, 0, stream>>>(acc, out);
}